// Round 2
// baseline (2539.524 us; speedup 1.0000x reference)
//
#include <hip/hip_runtime.h>
#include <hip/hip_bf16.h>

#define NPTS 8192
#define KS   1024
#define NB   16

// ---------------------------------------------------------------------------
// FPS: one block per batch, 1024 threads, 8 points/thread held in registers.
// Matches jnp semantics: d = sum((x-c)^2) computed sequentially, NO fp
// contraction, argmax = first occurrence (lowest index on ties).
// idx_out[b*KS + 0] = 0; idx_out[b*KS + s+1] = argmax after update with
// centroid idx_out[b*KS + s].
// Two barriers per step: every wave redundantly reduces the 16 per-wave
// results (no wave0-only publish barrier). All crd[] indexing is
// compile-time (unrolled) so the array stays in VGPRs (no scratch).
// ---------------------------------------------------------------------------
__global__ __launch_bounds__(1024, 1) void fps_kernel(const float* __restrict__ x,
                                                      int* __restrict__ idx_out) {
#pragma clang fp contract(off)
  const int b    = blockIdx.x;
  const int tid  = threadIdx.x;
  const int lane = tid & 63;
  const int wave = tid >> 6;
  const float* xb = x + (size_t)b * NPTS * 6;

  // Load this thread's 8 consecutive points (48 floats = 12 float4, 16B aligned)
  float crd[48];
  {
    const float4* src = reinterpret_cast<const float4*>(xb + tid * 48);
    #pragma unroll
    for (int i = 0; i < 12; ++i) {
      float4 v = src[i];
      crd[4*i+0] = v.x; crd[4*i+1] = v.y; crd[4*i+2] = v.z; crd[4*i+3] = v.w;
    }
  }
  float dist[8];
  #pragma unroll
  for (int j = 0; j < 8; ++j) dist[j] = __builtin_huge_valf();

  __shared__ float cbuf[6];
  __shared__ float wv[16];
  __shared__ int   wi[16];

  if (tid == 0) {
    idx_out[b * KS] = 0;
    #pragma unroll
    for (int d = 0; d < 6; ++d) cbuf[d] = crd[d];   // centroid 0 = point 0
  }
  __syncthreads();

  for (int step = 0; step < KS - 1; ++step) {
    const float c0 = cbuf[0], c1 = cbuf[1], c2 = cbuf[2],
                c3 = cbuf[3], c4 = cbuf[4], c5 = cbuf[5];
    float bestv = -__builtin_huge_valf();
    int   besti = 0;
    #pragma unroll
    for (int j = 0; j < 8; ++j) {
      float t0 = crd[6*j+0] - c0; float s = t0 * t0;
      float t1 = crd[6*j+1] - c1; s = s + t1 * t1;
      float t2 = crd[6*j+2] - c2; s = s + t2 * t2;
      float t3 = crd[6*j+3] - c3; s = s + t3 * t3;
      float t4 = crd[6*j+4] - c4; s = s + t4 * t4;
      float t5 = crd[6*j+5] - c5; s = s + t5 * t5;
      float nd = fminf(dist[j], s);
      dist[j] = nd;
      if (nd > bestv) { bestv = nd; besti = tid * 8 + j; }  // ascending j keeps lowest idx on tie
    }
    // wave64 argmax butterfly, tie -> lower index
    #pragma unroll
    for (int off = 1; off < 64; off <<= 1) {
      float ov = __shfl_xor(bestv, off, 64);
      int   oi = __shfl_xor(besti, off, 64);
      if (ov > bestv || (ov == bestv && oi < besti)) { bestv = ov; besti = oi; }
    }
    if (lane == 0) { wv[wave] = bestv; wi[wave] = besti; }
    __syncthreads();
    // EVERY wave reduces the 16 per-wave results (redundant, saves a barrier)
    float v2 = (lane < 16) ? wv[lane] : -__builtin_huge_valf();
    int   i2 = (lane < 16) ? wi[lane] : 0x7fffffff;
    #pragma unroll
    for (int off = 1; off < 16; off <<= 1) {
      float ov = __shfl_xor(v2, off, 64);
      int   oi = __shfl_xor(i2, off, 64);
      if (ov > v2 || (ov == v2 && oi < i2)) { v2 = ov; i2 = oi; }
    }
    const int bi = __shfl(i2, 0, 64);         // lanes 16..63 get lane0's result
    if (tid == 0) idx_out[b * KS + step + 1] = bi;
    if ((bi >> 3) == tid) {                   // owner publishes next centroid
      const int jj = bi & 7;
      #pragma unroll
      for (int j = 0; j < 8; ++j)             // compile-time index: crd stays in VGPRs
        if (j == jj) {
          #pragma unroll
          for (int d = 0; d < 6; ++d) cbuf[d] = crd[6*j+d];
        }
    }
    __syncthreads();
  }
}

// ---------------------------------------------------------------------------
// Sine-MLP on the 16384 sampled points only (8x less work than all-points).
// 64 points/block, 512 threads. Acts in LDS [p][c] (b128 broadcast reads);
// W tile transposed in LDS [c][Cout+1] (conflict-free vector reads).
// Each wave: 8 points x all outs.
// ---------------------------------------------------------------------------
template<int CINP, int CINT, int COUT, int CT, bool LAST>
__device__ __forceinline__ void run_layer(const float* __restrict__ W,
                                          const float* __restrict__ bias,
                                          const float* __restrict__ in,
                                          float* __restrict__ outlds,
                                          float* __restrict__ gout,
                                          float* __restrict__ wt,
                                          int qbase, int tid) {
  constexpr int S = (COUT + 63) / 64;
  const int lane = tid & 63;
  const int wave = tid >> 6;
  const int p0   = wave * 8;

  float acc[8][S];
  {
    float bv[S];
    #pragma unroll
    for (int s = 0; s < S; ++s) {
      int o = s * 64 + lane;
      bv[s] = (o < COUT) ? bias[o] : 0.f;
    }
    #pragma unroll
    for (int j = 0; j < 8; ++j)
      #pragma unroll
      for (int s = 0; s < S; ++s) acc[j][s] = bv[s];
  }

  for (int ct0 = 0; ct0 < CINT; ct0 += CT) {
    __syncthreads();
    #pragma unroll 1
    for (int e = tid; e < COUT * CT; e += 512) {
      int o  = e / CT;           // CT is compile-time
      int cc = e % CT;
      wt[cc * (COUT + 1) + o] = W[o * CINT + ct0 + cc];
    }
    __syncthreads();
    #pragma unroll
    for (int cc0 = 0; cc0 < CT; cc0 += 4) {
      if (CT - cc0 >= 4) {
        float a[8][4];
        #pragma unroll
        for (int j = 0; j < 8; ++j) {
          float4 t = *reinterpret_cast<const float4*>(&in[(p0 + j) * CINP + ct0 + cc0]);
          a[j][0] = t.x; a[j][1] = t.y; a[j][2] = t.z; a[j][3] = t.w;
        }
        #pragma unroll
        for (int u = 0; u < 4; ++u) {
          float wvv[S];
          #pragma unroll
          for (int s = 0; s < S; ++s)
            wvv[s] = wt[(cc0 + u) * (COUT + 1) + s * 64 + lane];
          #pragma unroll
          for (int j = 0; j < 8; ++j)
            #pragma unroll
            for (int s = 0; s < S; ++s)
              acc[j][s] = fmaf(a[j][u], wvv[s], acc[j][s]);
        }
      } else {   // remainder of 2 (layer 1, CT=6)
        float a[8][2];
        #pragma unroll
        for (int j = 0; j < 8; ++j) {
          float2 t = *reinterpret_cast<const float2*>(&in[(p0 + j) * CINP + ct0 + cc0]);
          a[j][0] = t.x; a[j][1] = t.y;
        }
        #pragma unroll
        for (int u = 0; u < 2; ++u) {
          float wvv[S];
          #pragma unroll
          for (int s = 0; s < S; ++s)
            wvv[s] = wt[(cc0 + u) * (COUT + 1) + s * 64 + lane];
          #pragma unroll
          for (int j = 0; j < 8; ++j)
            #pragma unroll
            for (int s = 0; s < S; ++s)
              acc[j][s] = fmaf(a[j][u], wvv[s], acc[j][s]);
        }
      }
    }
  }
  #pragma unroll
  for (int j = 0; j < 8; ++j) {
    #pragma unroll
    for (int s = 0; s < S; ++s) {
      int o = s * 64 + lane;
      if (o < COUT) {
        float r = sinf(acc[j][s]);
        if (LAST) gout[(size_t)(qbase + p0 + j) * 512 + o] = r;
        else      outlds[(p0 + j) * COUT + o] = r;
      }
    }
  }
}

__global__ __launch_bounds__(512, 1) void mlp_kernel(
    const float* __restrict__ x, const int* __restrict__ sidx,
    const float* __restrict__ W1, const float* __restrict__ B1,
    const float* __restrict__ W2, const float* __restrict__ B2,
    const float* __restrict__ W3, const float* __restrict__ B3,
    const float* __restrict__ W4, const float* __restrict__ B4,
    const float* __restrict__ W5, const float* __restrict__ B5,
    const float* __restrict__ W6, const float* __restrict__ B6,
    float* __restrict__ out) {
  __shared__ float A[64 * 128];
  __shared__ float Bb[64 * 256];
  __shared__ float wt[16 * 513];
  const int tid   = threadIdx.x;
  const int qbase = blockIdx.x * 64;

  if (tid < 64) {              // gather the sampled points, stride-8 rows
    int q  = qbase + tid;
    int bb = q >> 10;
    int id = sidx[q];
    const float* xr = x + ((size_t)bb * NPTS + id) * 6;
    #pragma unroll
    for (int d = 0; d < 6; ++d) A[tid * 8 + d] = xr[d];
  }
  // (first barrier inside run_layer covers the gather)
  run_layer<8,   6,  32,  6, false>(W1, B1, A,  Bb, nullptr, wt, qbase, tid);
  run_layer<32, 32,  64, 16, false>(W2, B2, Bb, A,  nullptr, wt, qbase, tid);
  run_layer<64, 64,  64, 16, false>(W3, B3, A,  Bb, nullptr, wt, qbase, tid);
  run_layer<64, 64, 128, 16, false>(W4, B4, Bb, A,  nullptr, wt, qbase, tid);
  run_layer<128,128, 256, 16, false>(W5, B5, A,  Bb, nullptr, wt, qbase, tid);
  run_layer<256,256, 512, 16, true >(W6, B6, Bb, nullptr, out, wt, qbase, tid);
}

extern "C" void kernel_launch(void* const* d_in, const int* in_sizes, int n_in,
                              void* d_out, int out_size, void* d_ws, size_t ws_size,
                              hipStream_t stream) {
  const float* x  = (const float*)d_in[0];
  const float* W1 = (const float*)d_in[1];  const float* B1 = (const float*)d_in[2];
  const float* W2 = (const float*)d_in[3];  const float* B2 = (const float*)d_in[4];
  const float* W3 = (const float*)d_in[5];  const float* B3 = (const float*)d_in[6];
  const float* W4 = (const float*)d_in[7];  const float* B4 = (const float*)d_in[8];
  const float* W5 = (const float*)d_in[9];  const float* B5 = (const float*)d_in[10];
  const float* W6 = (const float*)d_in[11]; const float* B6 = (const float*)d_in[12];
  int*   idxbuf = (int*)d_ws;               // 16*1024 int32 = 64 KB scratch
  float* out    = (float*)d_out;            // [16,1024,512] fp32

  fps_kernel<<<NB, 1024, 0, stream>>>(x, idxbuf);
  mlp_kernel<<<256, 512, 0, stream>>>(x, idxbuf,
                                      W1, B1, W2, B2, W3, B3,
                                      W4, B4, W5, B5, W6, B6, out);
}

// Round 4
// 2078.101 us; speedup vs baseline: 1.2220x; 1.2220x over previous
//
#include <hip/hip_runtime.h>
#include <hip/hip_bf16.h>

#define NPTS 8192
#define KS   1024
#define NB   16
#define MLPB 2048                 // 16*8192/64 point-tiles

// ===========================================================================
// Shared MLP layer template. NT threads (NW=NT/64 waves), JP points per wave,
// NW*JP == 64 points per block. Acts in LDS [p][c]; W tile transposed in LDS
// [c][COUT+1] (conflict-free). Accumulation order over (ct0, cc0, u) is
// identical for every (point, output) pair regardless of NT/JP -> numerics
// identical to the round-2-passed kernel.
// ===========================================================================
template<int NT, int JP, int CINP, int CINT, int COUT, int CT, bool LAST>
__device__ __forceinline__ void run_layer(const float* __restrict__ W,
                                          const float* __restrict__ bias,
                                          const float* __restrict__ in,
                                          float* __restrict__ outlds,
                                          float* __restrict__ gout,
                                          float* __restrict__ wt,
                                          int qbase, int tid) {
  constexpr int S = (COUT + 63) / 64;
  const int lane = tid & 63;
  const int wave = tid >> 6;
  const int p0   = wave * JP;

  float acc[JP][S];
  {
    float bv[S];
    #pragma unroll
    for (int s = 0; s < S; ++s) {
      int o = s * 64 + lane;
      bv[s] = (o < COUT) ? bias[o] : 0.f;
    }
    #pragma unroll
    for (int j = 0; j < JP; ++j)
      #pragma unroll
      for (int s = 0; s < S; ++s) acc[j][s] = bv[s];
  }

  for (int ct0 = 0; ct0 < CINT; ct0 += CT) {
    __syncthreads();
    #pragma unroll 1
    for (int e = tid; e < COUT * CT; e += NT) {
      int o  = e / CT;           // CT compile-time
      int cc = e % CT;
      wt[cc * (COUT + 1) + o] = W[o * CINT + ct0 + cc];
    }
    __syncthreads();
    #pragma unroll
    for (int cc0 = 0; cc0 < CT; cc0 += 4) {
      if (CT - cc0 >= 4) {
        float a[JP][4];
        #pragma unroll
        for (int j = 0; j < JP; ++j) {
          float4 t = *reinterpret_cast<const float4*>(&in[(p0 + j) * CINP + ct0 + cc0]);
          a[j][0] = t.x; a[j][1] = t.y; a[j][2] = t.z; a[j][3] = t.w;
        }
        #pragma unroll
        for (int u = 0; u < 4; ++u) {
          float wvv[S];
          #pragma unroll
          for (int s = 0; s < S; ++s)
            wvv[s] = wt[(cc0 + u) * (COUT + 1) + s * 64 + lane];
          #pragma unroll
          for (int j = 0; j < JP; ++j)
            #pragma unroll
            for (int s = 0; s < S; ++s)
              acc[j][s] = fmaf(a[j][u], wvv[s], acc[j][s]);
        }
      } else {   // remainder of 2 (layer 1, CT=6)
        float a[JP][2];
        #pragma unroll
        for (int j = 0; j < JP; ++j) {
          float2 t = *reinterpret_cast<const float2*>(&in[(p0 + j) * CINP + ct0 + cc0]);
          a[j][0] = t.x; a[j][1] = t.y;
        }
        #pragma unroll
        for (int u = 0; u < 2; ++u) {
          float wvv[S];
          #pragma unroll
          for (int s = 0; s < S; ++s)
            wvv[s] = wt[(cc0 + u) * (COUT + 1) + s * 64 + lane];
          #pragma unroll
          for (int j = 0; j < JP; ++j)
            #pragma unroll
            for (int s = 0; s < S; ++s)
              acc[j][s] = fmaf(a[j][u], wvv[s], acc[j][s]);
        }
      }
    }
  }
  #pragma unroll
  for (int j = 0; j < JP; ++j) {
    #pragma unroll
    for (int s = 0; s < S; ++s) {
      int o = s * 64 + lane;
      if (o < COUT) {
        float r = sinf(acc[j][s]);
        if (LAST) gout[(size_t)(qbase + p0 + j) * 512 + o] = r;
        else      outlds[(p0 + j) * COUT + o] = r;
      }
    }
  }
}

// ===========================================================================
// FPS body (used by both fused and fallback kernels). 1024 threads, 8 pts/thr
// in registers (pinned with "+v" asm so the compiler cannot rematerialize
// them from global each step -- round-2 showed VGPR_Count=48 => reload).
// Semantics: d = sum((x-c)^2) sequential, fp-contract off; dist=min(dist,d);
// argmax first-occurrence. One barrier/step: packed u64 (distbits<<32|~idx)
// butterfly; per-wave results double-buffered by step parity; centroid read
// from global x at a wave-uniform (SGPR) index.
// ===========================================================================
__device__ __forceinline__ void fps_body(const float* __restrict__ x,
                                         int* __restrict__ idx_out,
                                         unsigned long long* __restrict__ wvi,  // [2][16] in LDS
                                         int b, int tid) {
#pragma clang fp contract(off)
  const int lane = tid & 63;
  const int wave = tid >> 6;
  const float* xb = x + (size_t)b * NPTS * 6;

  float crd[48];
  {
    const float4* src = reinterpret_cast<const float4*>(xb + tid * 48);
    #pragma unroll
    for (int i = 0; i < 12; ++i) {
      float4 v = src[i];
      crd[4*i+0] = v.x; crd[4*i+1] = v.y; crd[4*i+2] = v.z; crd[4*i+3] = v.w;
    }
  }
  #pragma unroll
  for (int i = 0; i < 48; ++i) asm volatile("" : "+v"(crd[i]));  // pin in VGPRs

  float dist[8];
  #pragma unroll
  for (int j = 0; j < 8; ++j) dist[j] = __builtin_huge_valf();

  if (tid == 0) idx_out[b * KS] = 0;
  int bi = 0;                                  // wave-uniform winner index

  for (int step = 0; step < KS - 1; ++step) {
    const float* cp = xb + bi * 6;             // uniform -> scalar loads, cache-hot
    const float c0 = cp[0], c1 = cp[1], c2 = cp[2],
                c3 = cp[3], c4 = cp[4], c5 = cp[5];

    float bestv = -1.0f;                       // all dists >= 0
    int   besti = 0;
    #pragma unroll
    for (int j = 0; j < 8; ++j) {
      float t0 = crd[6*j+0] - c0; float s = t0 * t0;
      float t1 = crd[6*j+1] - c1; s = s + t1 * t1;
      float t2 = crd[6*j+2] - c2; s = s + t2 * t2;
      float t3 = crd[6*j+3] - c3; s = s + t3 * t3;
      float t4 = crd[6*j+4] - c4; s = s + t4 * t4;
      float t5 = crd[6*j+5] - c5; s = s + t5 * t5;
      float nd = fminf(dist[j], s);
      dist[j] = nd;
      if (nd > bestv) { bestv = nd; besti = tid * 8 + j; }  // ascending j: lowest idx on tie
    }

    unsigned long long pk =
        ((unsigned long long)__float_as_uint(bestv) << 32) | (unsigned)(~besti);
    #pragma unroll
    for (int off = 1; off < 64; off <<= 1) {
      unsigned long long o = __shfl_xor(pk, off, 64);
      if (o > pk) pk = o;
    }
    if (lane == 0) wvi[(step & 1) * 16 + wave] = pk;
    __syncthreads();

    unsigned long long cr = (lane < 16) ? wvi[(step & 1) * 16 + lane] : 0ull;
    #pragma unroll
    for (int off = 1; off < 16; off <<= 1) {
      unsigned long long o = __shfl_xor(cr, off, 64);
      if (o > cr) cr = o;
    }
    bi = ~__builtin_amdgcn_readfirstlane((unsigned)cr);
    if (tid == 0) idx_out[b * KS + step + 1] = bi;
  }
}

// ===========================================================================
// FUSED kernel: blocks 0..15 = FPS (one per batch); blocks 16..2063 = MLP on
// ALL points (64 pts/block, 16 waves x 4 pts) -> feat[B*N][512] in workspace.
// 128KB static LDS forces 1 block/CU, so MLP blocks never share a CU with an
// FPS block (FPS stays latency-critical-path clean).
// ===========================================================================
__global__ __launch_bounds__(1024, 1) void fused_kernel(
    const float* __restrict__ x, int* __restrict__ idx_out,
    float* __restrict__ feat,
    const float* __restrict__ W1, const float* __restrict__ B1,
    const float* __restrict__ W2, const float* __restrict__ B2,
    const float* __restrict__ W3, const float* __restrict__ B3,
    const float* __restrict__ W4, const float* __restrict__ B4,
    const float* __restrict__ W5, const float* __restrict__ B5,
    const float* __restrict__ W6, const float* __restrict__ B6) {
  __shared__ __align__(16) float A[64 * 128];
  __shared__ float Bb[64 * 256];
  __shared__ float wt[16 * 513];
  const int tid = threadIdx.x;

  if (blockIdx.x < NB) {
    fps_body(x, idx_out, reinterpret_cast<unsigned long long*>(A), blockIdx.x, tid);
    return;
  }

  const int qbase = (blockIdx.x - NB) * 64;    // linear point index over B*N
  if (tid < 64) {
    const float* xr = x + (size_t)(qbase + tid) * 6;
    #pragma unroll
    for (int d = 0; d < 6; ++d) A[tid * 8 + d] = xr[d];
  }
  run_layer<1024, 4, 8,   6,  32,  6, false>(W1, B1, A,  Bb, nullptr, wt, qbase, tid);
  run_layer<1024, 4, 32,  32,  64, 16, false>(W2, B2, Bb, A,  nullptr, wt, qbase, tid);
  run_layer<1024, 4, 64,  64,  64, 16, false>(W3, B3, A,  Bb, nullptr, wt, qbase, tid);
  run_layer<1024, 4, 64,  64, 128, 16, false>(W4, B4, Bb, A,  nullptr, wt, qbase, tid);
  run_layer<1024, 4, 128, 128, 256, 16, false>(W5, B5, A,  Bb, nullptr, wt, qbase, tid);
  run_layer<1024, 4, 256, 256, 512, 16, true >(W6, B6, Bb, nullptr, feat, wt, qbase, tid);
}

// Gather the 16384 sampled rows: out[b,q,:] = feat[b*8192+idx[b,q], :]
__global__ __launch_bounds__(256) void gather_kernel(const float* __restrict__ feat,
                                                     const int* __restrict__ sidx,
                                                     float* __restrict__ out) {
  const int r = blockIdx.x * 2 + (threadIdx.x >> 7);    // 16384 rows
  const int c = (threadIdx.x & 127) * 4;
  const int b = r >> 10;
  const int id = sidx[r];
  const float4 v = *reinterpret_cast<const float4*>(feat + ((size_t)(b * NPTS + id)) * 512 + c);
  *reinterpret_cast<float4*>(out + (size_t)r * 512 + c) = v;
}

// ------------------------- fallback (sequential) path -----------------------
__global__ __launch_bounds__(1024, 1) void fps_kernel(const float* __restrict__ x,
                                                      int* __restrict__ idx_out) {
  __shared__ unsigned long long wvi[2 * 16];
  fps_body(x, idx_out, wvi, blockIdx.x, threadIdx.x);
}

__global__ __launch_bounds__(512, 1) void mlp_kernel(
    const float* __restrict__ x, const int* __restrict__ sidx,
    const float* __restrict__ W1, const float* __restrict__ B1,
    const float* __restrict__ W2, const float* __restrict__ B2,
    const float* __restrict__ W3, const float* __restrict__ B3,
    const float* __restrict__ W4, const float* __restrict__ B4,
    const float* __restrict__ W5, const float* __restrict__ B5,
    const float* __restrict__ W6, const float* __restrict__ B6,
    float* __restrict__ out) {
  __shared__ float A[64 * 128];
  __shared__ float Bb[64 * 256];
  __shared__ float wt[16 * 513];
  const int tid   = threadIdx.x;
  const int qbase = blockIdx.x * 64;

  if (tid < 64) {              // gather sampled points, stride-8 rows
    int q  = qbase + tid;
    int bb = q >> 10;
    int id = sidx[q];
    const float* xr = x + ((size_t)bb * NPTS + id) * 6;
    #pragma unroll
    for (int d = 0; d < 6; ++d) A[tid * 8 + d] = xr[d];
  }
  run_layer<512, 8, 8,   6,  32,  6, false>(W1, B1, A,  Bb, nullptr, wt, qbase, tid);
  run_layer<512, 8, 32,  32,  64, 16, false>(W2, B2, Bb, A,  nullptr, wt, qbase, tid);
  run_layer<512, 8, 64,  64,  64, 16, false>(W3, B3, A,  Bb, nullptr, wt, qbase, tid);
  run_layer<512, 8, 64,  64, 128, 16, false>(W4, B4, Bb, A,  nullptr, wt, qbase, tid);
  run_layer<512, 8, 128, 128, 256, 16, false>(W5, B5, A,  Bb, nullptr, wt, qbase, tid);
  run_layer<512, 8, 256, 256, 512, 16, true >(W6, B6, Bb, nullptr, out, wt, qbase, tid);
}

extern "C" void kernel_launch(void* const* d_in, const int* in_sizes, int n_in,
                              void* d_out, int out_size, void* d_ws, size_t ws_size,
                              hipStream_t stream) {
  const float* x  = (const float*)d_in[0];
  const float* W1 = (const float*)d_in[1];  const float* B1 = (const float*)d_in[2];
  const float* W2 = (const float*)d_in[3];  const float* B2 = (const float*)d_in[4];
  const float* W3 = (const float*)d_in[5];  const float* B3 = (const float*)d_in[6];
  const float* W4 = (const float*)d_in[7];  const float* B4 = (const float*)d_in[8];
  const float* W5 = (const float*)d_in[9];  const float* B5 = (const float*)d_in[10];
  const float* W6 = (const float*)d_in[11]; const float* B6 = (const float*)d_in[12];
  int*   idxbuf = (int*)d_ws;                              // 64 KB
  float* out    = (float*)d_out;                           // [16,1024,512] fp32

  const size_t featBytes = (size_t)NB * NPTS * 512 * sizeof(float);  // 268.4 MB
  if (ws_size >= 65536 + featBytes) {
    float* feat = (float*)((char*)d_ws + 65536);
    fused_kernel<<<NB + MLPB, 1024, 0, stream>>>(x, idxbuf, feat,
                                                 W1, B1, W2, B2, W3, B3,
                                                 W4, B4, W5, B5, W6, B6);
    gather_kernel<<<8192, 256, 0, stream>>>(feat, idxbuf, out);
  } else {
    fps_kernel<<<NB, 1024, 0, stream>>>(x, idxbuf);
    mlp_kernel<<<256, 512, 0, stream>>>(x, idxbuf,
                                        W1, B1, W2, B2, W3, B3,
                                        W4, B4, W5, B5, W6, B6, out);
  }
}

// Round 6
// 1951.510 us; speedup vs baseline: 1.3013x; 1.0649x over previous
//
#include <hip/hip_runtime.h>
#include <hip/hip_bf16.h>

#define NPTS 8192
#define KS   1024
#define NB   16

// ===========================================================================
// FPS: one block per batch, 1024 threads, 8 pts/thread in registers.
// Semantics (bit-exact vs jnp): d = sum((x-c)^2) sequential, fp-contract OFF;
// dist = min(dist, d); argmax first-occurrence (lowest index on ties).
//
// Round-5 structure:
//  - amdgpu_waves_per_eu(4,4): 128-VGPR budget, ~95 needed -> coords stay
//    register-resident (round-4 showed VGPR=40 => compiler re-streamed
//    ~196KB/step from L2, ~3500 cyc/step of the 4030 total).
//  - value-only f32 max butterfly (1 LDS op + 1 v_max per stage), then
//    __ballot(bestv==wmax) + ctz + v_readlane to recover the index.
//    Lane order == index order (thread t holds indices 8t..8t+7, ascending j
//    scan keeps lowest j), and wave order == index-block order, so
//    lowest-set-lane == first occurrence. Exact jnp.argmax tie-break.
//  - ONE barrier/step; per-wave results parity-double-buffered (max skew
//    between waves is 1 step, so write target p^1 never clobbers unread p).
//  - centroid loaded from global x at SGPR-uniform index (constant-cache hit).
// ===========================================================================
__global__ __launch_bounds__(1024, 4)
__attribute__((amdgpu_waves_per_eu(4, 4)))
void fps_kernel(const float* __restrict__ x, int* __restrict__ idx_out) {
#pragma clang fp contract(off)
  const int b    = blockIdx.x;
  const int tid  = threadIdx.x;
  const int lane = tid & 63;
  const int wave = tid >> 6;
  const float* xb = x + (size_t)b * NPTS * 6;

  // This thread's 8 consecutive points (48 floats = 12 float4, 16B aligned)
  float crd[48];
  {
    const float4* src = reinterpret_cast<const float4*>(xb + tid * 48);
    #pragma unroll
    for (int i = 0; i < 12; ++i) {
      float4 v = src[i];
      crd[4*i+0] = v.x; crd[4*i+1] = v.y; crd[4*i+2] = v.z; crd[4*i+3] = v.w;
    }
  }
  #pragma unroll
  for (int i = 0; i < 48; ++i) asm volatile("" : "+v"(crd[i]));  // discourage sinking

  float dist[8];
  #pragma unroll
  for (int j = 0; j < 8; ++j) dist[j] = __builtin_huge_valf();

  __shared__ uint2 wvi[2][16];     // [step parity][wave] = {idx, valbits}

  if (tid == 0) idx_out[b * KS] = 0;
  int bi = 0;                      // wave-uniform (SGPR) winner index

  for (int step = 0; step < KS - 1; ++step) {
    const float* cp = xb + bi * 6;             // uniform -> scalar loads
    const float c0 = cp[0], c1 = cp[1], c2 = cp[2],
                c3 = cp[3], c4 = cp[4], c5 = cp[5];

    float bestv = -1.0f;                       // all dists >= 0
    int   besti = 0;
    #pragma unroll
    for (int j = 0; j < 8; ++j) {
      float t0 = crd[6*j+0] - c0; float s = t0 * t0;
      float t1 = crd[6*j+1] - c1; s = s + t1 * t1;
      float t2 = crd[6*j+2] - c2; s = s + t2 * t2;
      float t3 = crd[6*j+3] - c3; s = s + t3 * t3;
      float t4 = crd[6*j+4] - c4; s = s + t4 * t4;
      float t5 = crd[6*j+5] - c5; s = s + t5 * t5;
      float nd = fminf(dist[j], s);
      dist[j] = nd;
      if (nd > bestv) { bestv = nd; besti = tid * 8 + j; }  // ascending j: lowest idx on tie
    }

    // wave64 value-only max butterfly (6 x (swizzle + v_max))
    float wmax = bestv;
    #pragma unroll
    for (int off = 1; off < 64; off <<= 1)
      wmax = fmaxf(wmax, __shfl_xor(wmax, off, 64));
    // recover index: lowest lane whose bestv equals the max == first occurrence
    unsigned long long ball = __ballot(bestv == wmax);
    int wlane = (int)__builtin_ctzll(ball);
    int widx  = __builtin_amdgcn_readlane(besti, wlane);

    if (lane == 0) wvi[step & 1][wave] = make_uint2((unsigned)widx, __float_as_uint(wmax));
    __syncthreads();

    // every wave reduces the 16 per-wave results (redundant; no 2nd barrier)
    uint2 wr = wvi[step & 1][lane & 15];
    float cv = __uint_as_float(wr.y);
    #pragma unroll
    for (int off = 1; off < 16; off <<= 1)
      cv = fmaxf(cv, __shfl_xor(cv, off, 64));
    unsigned long long b2 = __ballot(__uint_as_float(wr.y) == cv);
    int cl = (int)__builtin_ctzll(b2);         // in [0,16): lowest wave among ties
    bi = __builtin_amdgcn_readlane((int)wr.x, cl);

    if (tid == 0) idx_out[b * KS + step + 1] = bi;
  }
}

// ===========================================================================
// Sine-MLP on the 16384 sampled points only. 64 pts/block, 512 threads
// (8 waves x 8 pts). Acts in LDS [p][c]; W tile transposed in LDS [c][COUT+1]
// (conflict-free). Unchanged from round-2/4 (passed, ~360us).
// ===========================================================================
template<int NT, int JP, int CINP, int CINT, int COUT, int CT, bool LAST>
__device__ __forceinline__ void run_layer(const float* __restrict__ W,
                                          const float* __restrict__ bias,
                                          const float* __restrict__ in,
                                          float* __restrict__ outlds,
                                          float* __restrict__ gout,
                                          float* __restrict__ wt,
                                          int qbase, int tid) {
  constexpr int S = (COUT + 63) / 64;
  const int lane = tid & 63;
  const int wave = tid >> 6;
  const int p0   = wave * JP;

  float acc[JP][S];
  {
    float bv[S];
    #pragma unroll
    for (int s = 0; s < S; ++s) {
      int o = s * 64 + lane;
      bv[s] = (o < COUT) ? bias[o] : 0.f;
    }
    #pragma unroll
    for (int j = 0; j < JP; ++j)
      #pragma unroll
      for (int s = 0; s < S; ++s) acc[j][s] = bv[s];
  }

  for (int ct0 = 0; ct0 < CINT; ct0 += CT) {
    __syncthreads();
    #pragma unroll 1
    for (int e = tid; e < COUT * CT; e += NT) {
      int o  = e / CT;           // CT compile-time
      int cc = e % CT;
      wt[cc * (COUT + 1) + o] = W[o * CINT + ct0 + cc];
    }
    __syncthreads();
    #pragma unroll
    for (int cc0 = 0; cc0 < CT; cc0 += 4) {
      if (CT - cc0 >= 4) {
        float a[JP][4];
        #pragma unroll
        for (int j = 0; j < JP; ++j) {
          float4 t = *reinterpret_cast<const float4*>(&in[(p0 + j) * CINP + ct0 + cc0]);
          a[j][0] = t.x; a[j][1] = t.y; a[j][2] = t.z; a[j][3] = t.w;
        }
        #pragma unroll
        for (int u = 0; u < 4; ++u) {
          float wvv[S];
          #pragma unroll
          for (int s = 0; s < S; ++s)
            wvv[s] = wt[(cc0 + u) * (COUT + 1) + s * 64 + lane];
          #pragma unroll
          for (int j = 0; j < JP; ++j)
            #pragma unroll
            for (int s = 0; s < S; ++s)
              acc[j][s] = fmaf(a[j][u], wvv[s], acc[j][s]);
        }
      } else {   // remainder of 2 (layer 1, CT=6)
        float a[JP][2];
        #pragma unroll
        for (int j = 0; j < JP; ++j) {
          float2 t = *reinterpret_cast<const float2*>(&in[(p0 + j) * CINP + ct0 + cc0]);
          a[j][0] = t.x; a[j][1] = t.y;
        }
        #pragma unroll
        for (int u = 0; u < 2; ++u) {
          float wvv[S];
          #pragma unroll
          for (int s = 0; s < S; ++s)
            wvv[s] = wt[(cc0 + u) * (COUT + 1) + s * 64 + lane];
          #pragma unroll
          for (int j = 0; j < JP; ++j)
            #pragma unroll
            for (int s = 0; s < S; ++s)
              acc[j][s] = fmaf(a[j][u], wvv[s], acc[j][s]);
        }
      }
    }
  }
  #pragma unroll
  for (int j = 0; j < JP; ++j) {
    #pragma unroll
    for (int s = 0; s < S; ++s) {
      int o = s * 64 + lane;
      if (o < COUT) {
        float r = sinf(acc[j][s]);
        if (LAST) gout[(size_t)(qbase + p0 + j) * 512 + o] = r;
        else      outlds[(p0 + j) * COUT + o] = r;
      }
    }
  }
}

__global__ __launch_bounds__(512, 1) void mlp_kernel(
    const float* __restrict__ x, const int* __restrict__ sidx,
    const float* __restrict__ W1, const float* __restrict__ B1,
    const float* __restrict__ W2, const float* __restrict__ B2,
    const float* __restrict__ W3, const float* __restrict__ B3,
    const float* __restrict__ W4, const float* __restrict__ B4,
    const float* __restrict__ W5, const float* __restrict__ B5,
    const float* __restrict__ W6, const float* __restrict__ B6,
    float* __restrict__ out) {
  __shared__ float A[64 * 128];
  __shared__ float Bb[64 * 256];
  __shared__ float wt[16 * 513];
  const int tid   = threadIdx.x;
  const int qbase = blockIdx.x * 64;

  if (tid < 64) {              // gather sampled points, stride-8 rows
    int q  = qbase + tid;
    int bb = q >> 10;
    int id = sidx[q];
    const float* xr = x + ((size_t)bb * NPTS + id) * 6;
    #pragma unroll
    for (int d = 0; d < 6; ++d) A[tid * 8 + d] = xr[d];
  }
  run_layer<512, 8, 8,   6,  32,  6, false>(W1, B1, A,  Bb, nullptr, wt, qbase, tid);
  run_layer<512, 8, 32,  32,  64, 16, false>(W2, B2, Bb, A,  nullptr, wt, qbase, tid);
  run_layer<512, 8, 64,  64,  64, 16, false>(W3, B3, A,  Bb, nullptr, wt, qbase, tid);
  run_layer<512, 8, 64,  64, 128, 16, false>(W4, B4, Bb, A,  nullptr, wt, qbase, tid);
  run_layer<512, 8, 128, 128, 256, 16, false>(W5, B5, A,  Bb, nullptr, wt, qbase, tid);
  run_layer<512, 8, 256, 256, 512, 16, true >(W6, B6, Bb, nullptr, out, wt, qbase, tid);
}

extern "C" void kernel_launch(void* const* d_in, const int* in_sizes, int n_in,
                              void* d_out, int out_size, void* d_ws, size_t ws_size,
                              hipStream_t stream) {
  const float* x  = (const float*)d_in[0];
  const float* W1 = (const float*)d_in[1];  const float* B1 = (const float*)d_in[2];
  const float* W2 = (const float*)d_in[3];  const float* B2 = (const float*)d_in[4];
  const float* W3 = (const float*)d_in[5];  const float* B3 = (const float*)d_in[6];
  const float* W4 = (const float*)d_in[7];  const float* B4 = (const float*)d_in[8];
  const float* W5 = (const float*)d_in[9];  const float* B5 = (const float*)d_in[10];
  const float* W6 = (const float*)d_in[11]; const float* B6 = (const float*)d_in[12];
  int*   idxbuf = (int*)d_ws;                              // 64 KB scratch
  float* out    = (float*)d_out;                           // [16,1024,512] fp32

  fps_kernel<<<NB, 1024, 0, stream>>>(x, idxbuf);
  mlp_kernel<<<256, 512, 0, stream>>>(x, idxbuf,
                                      W1, B1, W2, B2, W3, B3,
                                      W4, B4, W5, B5, W6, B6, out);
}